// Round 1
// baseline (501.095 us; speedup 1.0000x reference)
//
#include <hip/hip_runtime.h>
#include <hip/hip_bf16.h>
#include <stdint.h>

typedef __bf16 bf16x8 __attribute__((ext_vector_type(8)));
typedef float f32x4 __attribute__((ext_vector_type(4)));

#define S_LEN 8192
#define BATCH 4
#define DMODEL 512
#define NHEAD 8
#define DHEAD 64
#define MROWS (BATCH * S_LEN)              // 32768
#define OUT0_ELEMS (MROWS * DMODEL)        // 16777216
#define KV_ELEMS (BATCH * NHEAD * DHEAD * DHEAD)  // 131072
#define Z_ELEMS (BATCH * NHEAD * DHEAD)    // 2048

__device__ __forceinline__ uint16_t f2bf(float f) {
    uint32_t u = __float_as_uint(f);
    u = (u + 0x7fffu + ((u >> 16) & 1u)) >> 16;   // RNE
    return (uint16_t)u;
}
__device__ __forceinline__ uint32_t pack2(float a, float b) {
    union { __hip_bfloat162 h; uint32_t u; } cv;
    cv.h = __float22bfloat162_rn(make_float2(a, b));
    return cv.u;
}
__device__ __forceinline__ void gload_lds16(const void* g, void* l) {
    __builtin_amdgcn_global_load_lds(
        (const __attribute__((address_space(1))) void*)g,
        (__attribute__((address_space(3))) void*)l, 16, 0, 0);
}

// ---------------- weights fp32 -> bf16 (all four at once) ----------------
__global__ void wconv_kernel(const float* __restrict__ w0, const float* __restrict__ w1,
                             const float* __restrict__ w2, const float* __restrict__ w3,
                             uint16_t* __restrict__ dst) {
    const float* src = (blockIdx.y == 0) ? w0 : (blockIdx.y == 1) ? w1
                       : (blockIdx.y == 2) ? w2 : w3;
    uint16_t* d = dst + (size_t)blockIdx.y * (DMODEL * DMODEL);
    int i = (blockIdx.x * 256 + threadIdx.x) * 4;
    float4 v = *(const float4*)(src + i);
    uint2 o;
    o.x = pack2(v.x, v.y);
    o.y = pack2(v.z, v.w);
    *(uint2*)(d + i) = o;
}

// ---------------- GEMM: C[m][n] = act(sum_k A[m][k]*W[n][k] + bias[n]) ----------
// Barrier-free k-loop: B (weight slice, 128n x 512k) staged in LDS once per K-half
// (64 KB, 2 stages -> 4 barriers TOTAL vs 32 before). A fragments are loaded
// DIRECTLY from global into registers (MFMA A-layout = lane l15 -> row, quad*8 ->
// contiguous k = exactly 2x float4 / 1x uint4 of a row-major row) and packed to
// bf16 in-reg. Next-k A loads issued before current MFMAs -> latency self-hides,
// waves free-run with no per-iteration sync.
// Grid (m=256, n=4): the 4 n-blocks sharing an A m-tile land on the SAME XCD
// (round-robin id%8, 256%8==0) -> A rereads hit that XCD's L2 / LLC.
template<bool A_F32, bool ELU1, bool OUT_F32, bool OUT_TRANS>
__global__ __launch_bounds__(256, 2)
void gemm_kernel(const void* __restrict__ Ap, const uint16_t* __restrict__ Wb,
                 const float* __restrict__ bias, void* __restrict__ Cp)
{
    __shared__ uint4 smem4[4096];            // 64 KB: B fragments, then epilogue scratch
    uint16_t* sB = (uint16_t*)smem4;
    const int tid = threadIdx.x;
    const int lane = tid & 63, w = tid >> 6;
    const int quad = lane >> 4, l15 = lane & 15;
    const int m_blk = blockIdx.x * 128, n_blk = blockIdx.y * 128;
    const int mw = (w & 1) * 64, nw = (w >> 1) * 64;

    f32x4 acc[4][4];
#pragma unroll
    for (int mi = 0; mi < 4; ++mi)
#pragma unroll
        for (int ni = 0; ni < 4; ++ni) acc[mi][ni] = (f32x4){0.f, 0.f, 0.f, 0.f};

    // per-lane A fragment base pointers (row = block m + wave m + mi*16 + l15)
    const float* a32[4];
    const uint16_t* a16[4];
#pragma unroll
    for (int mi = 0; mi < 4; ++mi) {
        const size_t row = (size_t)(m_blk + mw + mi * 16 + l15);
        if (A_F32) a32[mi] = (const float*)Ap + row * 512 + quad * 8;
        else       a16[mi] = (const uint16_t*)Ap + row * 512 + quad * 8;
    }

    // prefetch k-iter 0
    float4 ac[4][2];
    uint4  ac16[4];
#pragma unroll
    for (int mi = 0; mi < 4; ++mi) {
        if (A_F32) {
            ac[mi][0] = *(const float4*)(a32[mi]);
            ac[mi][1] = *(const float4*)(a32[mi] + 4);
        } else {
            ac16[mi] = *(const uint4*)(a16[mi]);
        }
    }

#pragma unroll
    for (int h = 0; h < 2; ++h) {
        if (h) __syncthreads();              // all waves done reading K-half 0
        // stage B half h: 64 fragments [nl(8)][kkl(8)][lane][8], wave w does nl=2w,2w+1
#pragma unroll
        for (int t = 0; t < 16; ++t) {
            const int f = w * 16 + t;
            const int nl = f >> 3, kkl = f & 7;
            gload_lds16(Wb + (size_t)(n_blk + nl * 16 + l15) * 512 + h * 256 + kkl * 32 + quad * 8,
                        sB + f * 512);
        }
        __syncthreads();                     // staging complete (vmcnt drained)
#pragma unroll
        for (int kkl = 0; kkl < 8; ++kkl) {
            const int kkg = h * 8 + kkl;
            float4 an[4][2];
            uint4  an16[4];
            if (kkg < 15) {                  // issue NEXT iter's A loads first
#pragma unroll
                for (int mi = 0; mi < 4; ++mi) {
                    if (A_F32) {
                        an[mi][0] = *(const float4*)(a32[mi] + (kkg + 1) * 32);
                        an[mi][1] = *(const float4*)(a32[mi] + (kkg + 1) * 32 + 4);
                    } else {
                        an16[mi] = *(const uint4*)(a16[mi] + (kkg + 1) * 32);
                    }
                }
            }
            bf16x8 afr[4];
#pragma unroll
            for (int mi = 0; mi < 4; ++mi) {
                union { uint4 u; bf16x8 v; } cv;
                if (A_F32) {
                    cv.u = make_uint4(pack2(ac[mi][0].x, ac[mi][0].y), pack2(ac[mi][0].z, ac[mi][0].w),
                                      pack2(ac[mi][1].x, ac[mi][1].y), pack2(ac[mi][1].z, ac[mi][1].w));
                } else {
                    cv.u = ac16[mi];
                }
                afr[mi] = cv.v;
            }
#pragma unroll
            for (int ni = 0; ni < 4; ++ni) {
                const bf16x8 bfr = *(const bf16x8*)(sB + ((((w >> 1) * 4 + ni) * 8 + kkl) * 64 + lane) * 8);
#pragma unroll
                for (int mi = 0; mi < 4; ++mi)
                    acc[mi][ni] = __builtin_amdgcn_mfma_f32_16x16x32_bf16(
                        afr[mi], bfr, acc[mi][ni], 0, 0, 0);
            }
            if (kkg < 15) {
#pragma unroll
                for (int mi = 0; mi < 4; ++mi) {
                    if (A_F32) { ac[mi][0] = an[mi][0]; ac[mi][1] = an[mi][1]; }
                    else       { ac16[mi] = an16[mi]; }
                }
            }
        }
    }
    __syncthreads();       // k-loop LDS dead; reuse as epilogue scratch

    float bias4[4];
#pragma unroll
    for (int ni = 0; ni < 4; ++ni) bias4[ni] = bias[n_blk + nw + ni * 16 + l15];

    if (OUT_TRANS) {
        // per-wave scratch: 64 cols x 32 rows, stride 40 (bank spread, 16B-aligned)
        uint16_t* t = (uint16_t*)smem4 + w * 2560;
        uint16_t* C = (uint16_t*)Cp;
        const int bb = m_blk >> 13;
        const int s_base = (m_blk & 8191) + mw;
#pragma unroll
        for (int p = 0; p < 2; ++p) {
#pragma unroll
            for (int mi2 = 0; mi2 < 2; ++mi2) {
                const int mi = p * 2 + mi2;
#pragma unroll
                for (int ni = 0; ni < 4; ++ni)
#pragma unroll
                    for (int r = 0; r < 4; ++r) {
                        float val = acc[mi][ni][r] + bias4[ni];
                        if (ELU1) val = (val > 0.f) ? (val + 1.f) : __expf(val);
                        t[(ni * 16 + l15) * 40 + mi2 * 16 + quad * 4 + r] = f2bf(val);
                    }
            }
#pragma unroll
            for (int it = 0; it < 4; ++it) {
                const int idx = it * 64 + lane;
                const int col = idx >> 2, sg = idx & 3;
                uint4 vv = *(const uint4*)(t + col * 40 + sg * 8);
                *(uint4*)(C + ((size_t)(bb * 512) + n_blk + nw + col) * 8192
                            + s_base + p * 32 + sg * 8) = vv;
            }
        }
    } else if (OUT_F32) {
        float* t = (float*)(smem4 + w * 256);
        float* C = (float*)Cp;
#pragma unroll
        for (int mi = 0; mi < 4; ++mi) {
#pragma unroll
            for (int ni = 0; ni < 4; ++ni)
#pragma unroll
                for (int r = 0; r < 4; ++r) {
                    float val = acc[mi][ni][r] + bias4[ni];
                    if (ELU1) val = (val > 0.f) ? (val + 1.f) : __expf(val);
                    t[(quad * 4 + r) * 64 + ni * 16 + l15] = val;
                }
#pragma unroll
            for (int c = 0; c < 4; ++c) {
                const int idx = c * 64 + lane;
                const int row = idx >> 4, colc = (idx & 15) * 4;
                float4 vv = *(const float4*)(t + row * 64 + colc);
                *(float4*)(C + (size_t)(m_blk + mw + mi * 16 + row) * 512
                             + n_blk + nw + colc) = vv;
            }
        }
    } else {
        uint16_t* t = (uint16_t*)(smem4 + w * 128);
        uint16_t* C = (uint16_t*)Cp;
#pragma unroll
        for (int mi = 0; mi < 4; ++mi) {
#pragma unroll
            for (int ni = 0; ni < 4; ++ni)
#pragma unroll
                for (int r = 0; r < 4; ++r) {
                    float val = acc[mi][ni][r] + bias4[ni];
                    if (ELU1) val = (val > 0.f) ? (val + 1.f) : __expf(val);
                    t[(quad * 4 + r) * 64 + ni * 16 + l15] = f2bf(val);
                }
#pragma unroll
            for (int c = 0; c < 2; ++c) {
                const int idx = c * 64 + lane;
                const int row = idx >> 3, colc = (idx & 7) * 8;
                uint4 vv = *(const uint4*)(t + row * 64 + colc);
                *(uint4*)(C + (size_t)(m_blk + mw + mi * 16 + row) * 512
                            + n_blk + nw + colc) = vv;
            }
        }
    }
}

// ---------------- kv state via MFMA: kv[d][m] = sum_s KT[d][s]*VT[m][s] ---------
// Barrier-free, LDS-free: KT/VT are row-major along s (the MFMA k-dim), so each
// lane's fragment is one contiguous 16B global load. KT/VT are LLC-resident
// (just written). z[d]=sum_s KT[d][s] folded in as MFMA vs all-ones B fragment.
// fp32 atomicAdd commit. Per (b,h): 64x64x8192, 16 s-splits of 512.
__global__ __launch_bounds__(256, 4)
void kv_kernel(const uint16_t* __restrict__ KT, const uint16_t* __restrict__ VT,
               float* __restrict__ kvz)
{
    const int tid = threadIdx.x;
    const int lane = tid & 63, w = tid >> 6;
    const int quad = lane >> 4, l15 = lane & 15;
    const int bh = blockIdx.y, b = bh >> 3, h = bh & 7;
    const int dh2 = w & 1, mh2 = w >> 1;
    const int S0 = blockIdx.x * 512;

    const uint16_t* Ka[2];
    const uint16_t* Va[2];
#pragma unroll
    for (int i = 0; i < 2; ++i) {
        Ka[i] = KT + (size_t)(b * 512 + h * 64 + dh2 * 32 + i * 16 + l15) * 8192 + S0 + quad * 8;
        Va[i] = VT + (size_t)(b * 512 + h * 64 + mh2 * 32 + i * 16 + l15) * 8192 + S0 + quad * 8;
    }

    f32x4 acc[2][2], accz[2];
#pragma unroll
    for (int mi = 0; mi < 2; ++mi) {
        accz[mi] = (f32x4){0.f, 0.f, 0.f, 0.f};
#pragma unroll
        for (int ni = 0; ni < 2; ++ni) acc[mi][ni] = (f32x4){0.f, 0.f, 0.f, 0.f};
    }
    bf16x8 ones;
#pragma unroll
    for (int j = 0; j < 8; ++j) ones[j] = (__bf16)1.0f;

    uint4 ka[2], va[2];
#pragma unroll
    for (int i = 0; i < 2; ++i) {
        ka[i] = *(const uint4*)(Ka[i]);
        va[i] = *(const uint4*)(Va[i]);
    }

#pragma unroll
    for (int it = 0; it < 16; ++it) {
        uint4 kn[2], vn[2];
        if (it < 15) {
#pragma unroll
            for (int i = 0; i < 2; ++i) {
                kn[i] = *(const uint4*)(Ka[i] + (it + 1) * 32);
                vn[i] = *(const uint4*)(Va[i] + (it + 1) * 32);
            }
        }
        bf16x8 afr[2], bfr[2];
#pragma unroll
        for (int i = 0; i < 2; ++i) {
            union { uint4 u; bf16x8 v; } ca, cb;
            ca.u = ka[i]; afr[i] = ca.v;
            cb.u = va[i]; bfr[i] = cb.v;
        }
#pragma unroll
        for (int mi = 0; mi < 2; ++mi)
#pragma unroll
            for (int ni = 0; ni < 2; ++ni)
                acc[mi][ni] = __builtin_amdgcn_mfma_f32_16x16x32_bf16(
                    afr[mi], bfr[ni], acc[mi][ni], 0, 0, 0);
        if (mh2 == 0) {
#pragma unroll
            for (int mi = 0; mi < 2; ++mi)
                accz[mi] = __builtin_amdgcn_mfma_f32_16x16x32_bf16(
                    afr[mi], ones, accz[mi], 0, 0, 0);
        }
        if (it < 15) {
#pragma unroll
            for (int i = 0; i < 2; ++i) { ka[i] = kn[i]; va[i] = vn[i]; }
        }
    }
    float* kvp = kvz + (size_t)bh * 4096;
#pragma unroll
    for (int mi = 0; mi < 2; ++mi)
#pragma unroll
        for (int ni = 0; ni < 2; ++ni)
#pragma unroll
            for (int r = 0; r < 4; ++r)
                atomicAdd(kvp + (dh2 * 32 + mi * 16 + quad * 4 + r) * 64
                              + mh2 * 32 + ni * 16 + l15, acc[mi][ni][r]);
    if (mh2 == 0 && l15 == 0) {
#pragma unroll
        for (int mi = 0; mi < 2; ++mi)
#pragma unroll
            for (int r = 0; r < 4; ++r)
                atomicAdd(kvz + KV_ELEMS + bh * 64 + dh2 * 32 + mi * 16 + quad * 4 + r,
                          accz[mi][r]);
    }
}

// ---------------- kv finalize: fp32 kv+z -> bf16 fragment-layout KVf ------------
// KVf[bh] flat order: [ng(5)][kk(2)][quad(4)][l15(16)][j(8)], n=ng*16+l15,
// d=kk*32+quad*8+j; n==64 -> z column, n>64 -> 0 pad.
__global__ void kvf_kernel(const float* __restrict__ kvz, uint16_t* __restrict__ KVf) {
    const int bh = blockIdx.x;
    const int tid = threadIdx.x;
    for (int e = tid; e < 5120; e += 256) {
        const int j = e & 7, c = e >> 3;
        const int l15c = c & 15, quadc = (c >> 4) & 3, kkc = (c >> 6) & 1, ng = c >> 7;
        const int n = ng * 16 + l15c;
        const int d = kkc * 32 + quadc * 8 + j;
        float val = (n < 64) ? kvz[(size_t)bh * 4096 + d * 64 + n]
                  : ((n == 64) ? kvz[KV_ELEMS + bh * 64 + d] : 0.f);
        KVf[(size_t)bh * 5120 + e] = f2bf(val);
    }
}

// ---------------- attention: y = (Q @ kv) / (Q . z + eps), per (b,h) ------------
__global__ __launch_bounds__(256, 4)
void attn_kernel(const uint16_t* __restrict__ Qb, const uint16_t* __restrict__ KVf,
                 uint16_t* __restrict__ Yb)
{
    __shared__ uint4 smem4[1152];             // 10 KB frag + 8 KB epilogue scratch
    uint16_t* sB = (uint16_t*)smem4;          // 5120 entries
    uint16_t* sEp = (uint16_t*)(smem4 + 640);
    const int bh = blockIdx.y;
    const int b = bh >> 3, h = bh & 7;
    const int tid = threadIdx.x;
    const int lane = tid & 63, w = tid >> 6, quad = lane >> 4, l15 = lane & 15;

    const uint16_t* src = KVf + (size_t)bh * 5120;
    gload_lds16(src + (size_t)tid * 8,         sB + (w * 64) * 8);
    gload_lds16(src + (size_t)(256 + tid) * 8, sB + ((256 + w * 64)) * 8);
    if (tid < 128)
        gload_lds16(src + (size_t)(512 + tid) * 8, sB + ((512 + w * 64)) * 8);
    __syncthreads();

    f32x4 acc[2][5];
#pragma unroll
    for (int mi = 0; mi < 2; ++mi)
#pragma unroll
        for (int ni = 0; ni < 5; ++ni) acc[mi][ni] = (f32x4){0.f, 0.f, 0.f, 0.f};
    const int row0 = blockIdx.x * 128 + w * 32;
#pragma unroll
    for (int kk = 0; kk < 2; ++kk) {
        bf16x8 afr[2];
#pragma unroll
        for (int mi = 0; mi < 2; ++mi) {
            const size_t ga = (size_t)(b * S_LEN + row0 + mi * 16 + l15) * DMODEL
                              + h * DHEAD + kk * 32 + quad * 8;
            afr[mi] = *(const bf16x8*)(Qb + ga);
        }
#pragma unroll
        for (int ni = 0; ni < 5; ++ni) {
            bf16x8 bfr = *(const bf16x8*)(sB + ((ni * 2 + kk) * 64 + lane) * 8);
            acc[0][ni] = __builtin_amdgcn_mfma_f32_16x16x32_bf16(afr[0], bfr, acc[0][ni], 0, 0, 0);
            acc[1][ni] = __builtin_amdgcn_mfma_f32_16x16x32_bf16(afr[1], bfr, acc[1][ni], 0, 0, 0);
        }
    }
    uint16_t* t = sEp + w * 1024;
#pragma unroll
    for (int mi = 0; mi < 2; ++mi) {
        float rden[4];
#pragma unroll
        for (int r = 0; r < 4; ++r) {
            const float den = __shfl(acc[mi][4][r], lane & 48, 64);  // col 64 = l15==0
            rden[r] = 1.0f / (den + 1e-6f);
        }
#pragma unroll
        for (int ni = 0; ni < 4; ++ni)
#pragma unroll
            for (int r = 0; r < 4; ++r)
                t[(quad * 4 + r) * 64 + ni * 16 + l15] = f2bf(acc[mi][ni][r] * rden[r]);
#pragma unroll
        for (int c = 0; c < 2; ++c) {
            const int idx = c * 64 + lane;
            const int row = idx >> 3, colc = (idx & 7) * 8;
            uint4 vv = *(const uint4*)(t + row * 64 + colc);
            *(uint4*)(Yb + (size_t)(b * S_LEN + row0 + mi * 16 + row) * 512
                        + h * DHEAD + colc) = vv;
        }
    }
}

extern "C" void kernel_launch(void* const* d_in, const int* in_sizes, int n_in,
                              void* d_out, int out_size, void* d_ws, size_t ws_size,
                              hipStream_t stream)
{
    const float* q  = (const float*)d_in[0];
    const float* k  = (const float*)d_in[1];
    const float* v  = (const float*)d_in[2];
    const float* Wq = (const float*)d_in[3];
    const float* bq = (const float*)d_in[4];
    const float* Wk = (const float*)d_in[5];
    const float* bk = (const float*)d_in[6];
    const float* Wv = (const float*)d_in[7];
    const float* bv = (const float*)d_in[8];
    const float* Wo = (const float*)d_in[9];
    const float* bo = (const float*)d_in[10];

    uint16_t* Qb = (uint16_t*)d_ws;          // bf16 [32768][512]
    uint16_t* KT = Qb + OUT0_ELEMS;          // bf16 [4][512][8192] keys^T
    uint16_t* VT = KT + OUT0_ELEMS;          // bf16 [4][512][8192] values^T
    uint16_t* Wb = VT + OUT0_ELEMS;          // 4 x [512][512] bf16
    uint16_t* KVf = VT;                      // VT dead after kv_kernel -> reuse
    uint16_t* Yb = KT;                       // KT dead after kv_kernel -> reuse

    float* out0 = (float*)d_out;
    float* kvz  = out0 + OUT0_ELEMS;         // kv (131072) then z (2048)

    hipMemsetAsync(kvz, 0, (KV_ELEMS + Z_ELEMS) * sizeof(float), stream);
    wconv_kernel<<<dim3(256, 4), 256, 0, stream>>>(Wq, Wk, Wv, Wo, Wb);
    gemm_kernel<true, true,  false, false><<<dim3(256, 4), 256, 0, stream>>>(q, Wb,              bq, Qb);
    gemm_kernel<true, true,  false, true ><<<dim3(256, 4), 256, 0, stream>>>(k, Wb + 262144,     bk, KT);
    gemm_kernel<true, false, false, true ><<<dim3(256, 4), 256, 0, stream>>>(v, Wb + 2 * 262144, bv, VT);
    kv_kernel<<<dim3(16, 32), 256, 0, stream>>>(KT, VT, kvz);
    kvf_kernel<<<dim3(32), 256, 0, stream>>>(kvz, KVf);
    attn_kernel<<<dim3(64, 32), 256, 0, stream>>>(Qb, KVf, Yb);
    gemm_kernel<false, false, true, false><<<dim3(256, 4), 256, 0, stream>>>(Yb, Wb + 3 * 262144, bo, out0);
}

// Round 4
// 430.554 us; speedup vs baseline: 1.1638x; 1.1638x over previous
//
#include <hip/hip_runtime.h>
#include <hip/hip_bf16.h>
#include <stdint.h>

typedef __bf16 bf16x8 __attribute__((ext_vector_type(8)));
typedef float f32x4 __attribute__((ext_vector_type(4)));

#define S_LEN 8192
#define BATCH 4
#define DMODEL 512
#define NHEAD 8
#define DHEAD 64
#define MROWS (BATCH * S_LEN)              // 32768
#define OUT0_ELEMS (MROWS * DMODEL)        // 16777216
#define KV_ELEMS (BATCH * NHEAD * DHEAD * DHEAD)  // 131072
#define Z_ELEMS (BATCH * NHEAD * DHEAD)    // 2048

__device__ __forceinline__ uint16_t f2bf(float f) {
    uint32_t u = __float_as_uint(f);
    u = (u + 0x7fffu + ((u >> 16) & 1u)) >> 16;   // RNE
    return (uint16_t)u;
}
__device__ __forceinline__ uint32_t pack2(float a, float b) {
    union { __hip_bfloat162 h; uint32_t u; } cv;
    cv.h = __float22bfloat162_rn(make_float2(a, b));
    return cv.u;
}
__device__ __forceinline__ void gload_lds16(const void* g, void* l) {
    __builtin_amdgcn_global_load_lds(
        (const __attribute__((address_space(1))) void*)g,
        (__attribute__((address_space(3))) void*)l, 16, 0, 0);
}

// ---------------- weights fp32 -> bf16 (all four at once) ----------------
__global__ void wconv_kernel(const float* __restrict__ w0, const float* __restrict__ w1,
                             const float* __restrict__ w2, const float* __restrict__ w3,
                             uint16_t* __restrict__ dst) {
    const float* src = (blockIdx.y == 0) ? w0 : (blockIdx.y == 1) ? w1
                       : (blockIdx.y == 2) ? w2 : w3;
    uint16_t* d = dst + (size_t)blockIdx.y * (DMODEL * DMODEL);
    int i = (blockIdx.x * 256 + threadIdx.x) * 4;
    float4 v = *(const float4*)(src + i);
    uint2 o;
    o.x = pack2(v.x, v.y);
    o.y = pack2(v.z, v.w);
    *(uint2*)(d + i) = o;
}

// ---------------- GEMM: C[m][n] = act(sum_k A[m][k]*W[n][k] + bias[n]) ----------
// 128x128 tile, BK=32, 4 waves each 64x64 (4x4 of 16x16x32 MFMA).
// T3-minimum 2-phase schedule: DOUBLE-BUFFERED 8KB A/B tiles (32 KB LDS, 3 blk/CU);
// each K-step issues stage(t+1) (B gload_lds + A reg-pack/ds_write) BEFORE the
// 16-MFMA compute of tile t, then ONE __syncthreads (vmcnt+lgkm drain) per step
// (17 barriers total vs 32 in the stage-then-compute version). A fp32 register
// prefetch runs TWO tiles ahead so pack2 never stalls on HBM.
// Grid (m=256, n=4): linear id = n*256+m, 256%8==0 -> the 4 n-blocks sharing an
// A m-tile land on the SAME XCD (round-robin id%8) -> A rereads hit that XCD's L2.
template<bool A_F32, bool ELU1, bool OUT_F32, bool OUT_TRANS>
__global__ __launch_bounds__(256, 3)
void gemm_kernel(const void* __restrict__ Ap, const uint16_t* __restrict__ Wb,
                 const float* __restrict__ bias, void* __restrict__ Cp)
{
    __shared__ uint4 smem4[2048];            // 32 KB: 2x(sA 8K + sB 8K); epilogue scratch
    uint16_t* sA0 = (uint16_t*)smem4;
    uint16_t* sB0 = sA0 + 4096;
    uint16_t* sA1 = sB0 + 4096;
    uint16_t* sB1 = sA1 + 4096;
    const int tid = threadIdx.x;
    const int lane = tid & 63, w = tid >> 6;
    const int quad = lane >> 4, l15 = lane & 15;
    const int m_blk = blockIdx.x * 128, n_blk = blockIdx.y * 128;
    const int g0 = w * 2;                    // this wave's two staging groups

    f32x4 acc[4][4];
#pragma unroll
    for (int mi = 0; mi < 4; ++mi)
#pragma unroll
        for (int ni = 0; ni < 4; ++ni) acc[mi][ni] = (f32x4){0.f, 0.f, 0.f, 0.f};

    const int ar = tid >> 1;                 // A fp32 staging: row 0..127
    const int ah = tid & 1;                  // k-half (16 cols)
    const float* arow_base = A_F32 ? ((const float*)Ap + (size_t)(m_blk + ar) * 512 + ah * 16)
                                   : nullptr;
    const uint16_t* Ab = (const uint16_t*)Ap;

    auto loadA = [&](int t, float4* r) {
        const float* p = arow_base + t * 32;
        r[0] = *(const float4*)(p);
        r[1] = *(const float4*)(p + 4);
        r[2] = *(const float4*)(p + 8);
        r[3] = *(const float4*)(p + 12);
    };
    auto packA = [&](uint16_t* sA, const float4* r) {
        uint16_t* base = sA + (((ar >> 4) * 4 + ah * 2) * 16 + (ar & 15)) * 8;
        *(uint4*)base = make_uint4(pack2(r[0].x, r[0].y), pack2(r[0].z, r[0].w),
                                   pack2(r[1].x, r[1].y), pack2(r[1].z, r[1].w));
        *(uint4*)(base + 128) = make_uint4(pack2(r[2].x, r[2].y), pack2(r[2].z, r[2].w),
                                           pack2(r[3].x, r[3].y), pack2(r[3].z, r[3].w));
    };
    auto stageB = [&](uint16_t* sB, int t) {
        const int k0 = t * 32;
        gload_lds16(Wb + (size_t)(n_blk + g0 * 16 + l15) * 512 + k0 + quad * 8,
                    sB + g0 * 512);
        gload_lds16(Wb + (size_t)(n_blk + (g0 + 1) * 16 + l15) * 512 + k0 + quad * 8,
                    sB + (g0 + 1) * 512);
    };
    auto stageA16 = [&](uint16_t* sA, int t) {
        const int k0 = t * 32;
        gload_lds16(Ab + (size_t)(m_blk + g0 * 16 + l15) * 512 + k0 + quad * 8,
                    sA + g0 * 512);
        gload_lds16(Ab + (size_t)(m_blk + (g0 + 1) * 16 + l15) * 512 + k0 + quad * 8,
                    sA + (g0 + 1) * 512);
    };
    auto compute = [&](const uint16_t* sA, const uint16_t* sB) {
        bf16x8 afr[4], bfr[4];
#pragma unroll
        for (int mi = 0; mi < 4; ++mi)
            afr[mi] = *(const bf16x8*)(sA + (((w & 1) * 4 + mi) * 64 + lane) * 8);
#pragma unroll
        for (int ni = 0; ni < 4; ++ni)
            bfr[ni] = *(const bf16x8*)(sB + (((w >> 1) * 4 + ni) * 64 + lane) * 8);
#pragma unroll
        for (int mi = 0; mi < 4; ++mi)
#pragma unroll
            for (int ni = 0; ni < 4; ++ni)
                acc[mi][ni] = __builtin_amdgcn_mfma_f32_16x16x32_bf16(
                    afr[mi], bfr[ni], acc[mi][ni], 0, 0, 0);
    };

    // Prologue: stage tile 0 into buf0. rX pipeline invariant: at pair-p entry,
    // rX holds (in-flight) A(2p+1).
    float4 rX[4], rY[4];
    if (A_F32) loadA(0, rY);
    stageB(sB0, 0);
    if (A_F32) { loadA(1, rX); packA(sA0, rY); }
    else       stageA16(sA0, 0);
    __syncthreads();

    for (int p = 0; p < 8; ++p) {
        const int t0 = 2 * p;
        // part 1: stage tile t0+1 -> buf1 (issued first), compute tile t0 from buf0
        if (A_F32 && p < 7) loadA(t0 + 2, rY);
        stageB(sB1, t0 + 1);
        if (A_F32) packA(sA1, rX);
        else       stageA16(sA1, t0 + 1);
        compute(sA0, sB0);
        __syncthreads();
        // part 2: stage tile t0+2 -> buf0, compute tile t0+1 from buf1
        if (p < 7) {
            if (A_F32) loadA(t0 + 3, rX);
            stageB(sB0, t0 + 2);
            if (A_F32) packA(sA0, rY);
            else       stageA16(sA0, t0 + 2);
        }
        compute(sA1, sB1);
        __syncthreads();
    }
    // last barrier already executed; k-loop LDS dead -> epilogue scratch

    const int mw = (w & 1) * 64, nw = (w >> 1) * 64;
    float bias4[4];
#pragma unroll
    for (int ni = 0; ni < 4; ++ni) bias4[ni] = bias[n_blk + nw + ni * 16 + l15];

    if (OUT_TRANS) {
        // per-wave scratch: 64 cols x 32 rows, stride 40 (bank spread, 16B-aligned)
        uint16_t* t = (uint16_t*)smem4 + w * 2560;
        uint16_t* C = (uint16_t*)Cp;
        const int bb = m_blk >> 13;
        const int s_base = (m_blk & 8191) + mw;
#pragma unroll
        for (int p = 0; p < 2; ++p) {
#pragma unroll
            for (int mi2 = 0; mi2 < 2; ++mi2) {
                const int mi = p * 2 + mi2;
#pragma unroll
                for (int ni = 0; ni < 4; ++ni)
#pragma unroll
                    for (int r = 0; r < 4; ++r) {
                        float val = acc[mi][ni][r] + bias4[ni];
                        if (ELU1) val = (val > 0.f) ? (val + 1.f) : __expf(val);
                        t[(ni * 16 + l15) * 40 + mi2 * 16 + quad * 4 + r] = f2bf(val);
                    }
            }
#pragma unroll
            for (int it = 0; it < 4; ++it) {
                const int idx = it * 64 + lane;
                const int col = idx >> 2, sg = idx & 3;
                uint4 vv = *(const uint4*)(t + col * 40 + sg * 8);
                *(uint4*)(C + ((size_t)(bb * 512) + n_blk + nw + col) * 8192
                            + s_base + p * 32 + sg * 8) = vv;
            }
        }
    } else if (OUT_F32) {
        float* t = (float*)(smem4 + w * 256);
        float* C = (float*)Cp;
#pragma unroll
        for (int mi = 0; mi < 4; ++mi) {
#pragma unroll
            for (int ni = 0; ni < 4; ++ni)
#pragma unroll
                for (int r = 0; r < 4; ++r) {
                    float val = acc[mi][ni][r] + bias4[ni];
                    if (ELU1) val = (val > 0.f) ? (val + 1.f) : __expf(val);
                    t[(quad * 4 + r) * 64 + ni * 16 + l15] = val;
                }
#pragma unroll
            for (int c = 0; c < 4; ++c) {
                const int idx = c * 64 + lane;
                const int row = idx >> 4, colc = (idx & 15) * 4;
                float4 vv = *(const float4*)(t + row * 64 + colc);
                *(float4*)(C + (size_t)(m_blk + mw + mi * 16 + row) * 512
                             + n_blk + nw + colc) = vv;
            }
        }
    } else {
        uint16_t* t = (uint16_t*)(smem4 + w * 128);
        uint16_t* C = (uint16_t*)Cp;
#pragma unroll
        for (int mi = 0; mi < 4; ++mi) {
#pragma unroll
            for (int ni = 0; ni < 4; ++ni)
#pragma unroll
                for (int r = 0; r < 4; ++r) {
                    float val = acc[mi][ni][r] + bias4[ni];
                    if (ELU1) val = (val > 0.f) ? (val + 1.f) : __expf(val);
                    t[(quad * 4 + r) * 64 + ni * 16 + l15] = f2bf(val);
                }
#pragma unroll
            for (int c = 0; c < 2; ++c) {
                const int idx = c * 64 + lane;
                const int row = idx >> 3, colc = (idx & 7) * 8;
                uint4 vv = *(const uint4*)(t + row * 64 + colc);
                *(uint4*)(C + (size_t)(m_blk + mw + mi * 16 + row) * 512
                            + n_blk + nw + colc) = vv;
            }
        }
    }
}

// ---------------- kv state via MFMA: kv[d][m] = sum_s KT[d][s]*VT[m][s] ---------
// Barrier-free, LDS-free: KT/VT are row-major along s (the MFMA k-dim), so each
// lane's fragment is one contiguous 16B global load. KT/VT are LLC-resident
// (just written). z[d]=sum_s KT[d][s] folded in as MFMA vs all-ones B fragment.
// fp32 atomicAdd commit. Per (b,h): 64x64x8192, 16 s-splits of 512.
__global__ __launch_bounds__(256, 4)
void kv_kernel(const uint16_t* __restrict__ KT, const uint16_t* __restrict__ VT,
               float* __restrict__ kvz)
{
    const int tid = threadIdx.x;
    const int lane = tid & 63, w = tid >> 6;
    const int quad = lane >> 4, l15 = lane & 15;
    const int bh = blockIdx.y, b = bh >> 3, h = bh & 7;
    const int dh2 = w & 1, mh2 = w >> 1;
    const int S0 = blockIdx.x * 512;

    const uint16_t* Ka[2];
    const uint16_t* Va[2];
#pragma unroll
    for (int i = 0; i < 2; ++i) {
        Ka[i] = KT + (size_t)(b * 512 + h * 64 + dh2 * 32 + i * 16 + l15) * 8192 + S0 + quad * 8;
        Va[i] = VT + (size_t)(b * 512 + h * 64 + mh2 * 32 + i * 16 + l15) * 8192 + S0 + quad * 8;
    }

    f32x4 acc[2][2], accz[2];
#pragma unroll
    for (int mi = 0; mi < 2; ++mi) {
        accz[mi] = (f32x4){0.f, 0.f, 0.f, 0.f};
#pragma unroll
        for (int ni = 0; ni < 2; ++ni) acc[mi][ni] = (f32x4){0.f, 0.f, 0.f, 0.f};
    }
    bf16x8 ones;
#pragma unroll
    for (int j = 0; j < 8; ++j) ones[j] = (__bf16)1.0f;

    uint4 ka[2], va[2];
#pragma unroll
    for (int i = 0; i < 2; ++i) {
        ka[i] = *(const uint4*)(Ka[i]);
        va[i] = *(const uint4*)(Va[i]);
    }

#pragma unroll
    for (int it = 0; it < 16; ++it) {
        uint4 kn[2], vn[2];
        if (it < 15) {
#pragma unroll
            for (int i = 0; i < 2; ++i) {
                kn[i] = *(const uint4*)(Ka[i] + (it + 1) * 32);
                vn[i] = *(const uint4*)(Va[i] + (it + 1) * 32);
            }
        }
        bf16x8 afr[2], bfr[2];
#pragma unroll
        for (int i = 0; i < 2; ++i) {
            union { uint4 u; bf16x8 v; } ca, cb;
            ca.u = ka[i]; afr[i] = ca.v;
            cb.u = va[i]; bfr[i] = cb.v;
        }
#pragma unroll
        for (int mi = 0; mi < 2; ++mi)
#pragma unroll
            for (int ni = 0; ni < 2; ++ni)
                acc[mi][ni] = __builtin_amdgcn_mfma_f32_16x16x32_bf16(
                    afr[mi], bfr[ni], acc[mi][ni], 0, 0, 0);
        if (mh2 == 0) {
#pragma unroll
            for (int mi = 0; mi < 2; ++mi)
                accz[mi] = __builtin_amdgcn_mfma_f32_16x16x32_bf16(
                    afr[mi], ones, accz[mi], 0, 0, 0);
        }
        if (it < 15) {
#pragma unroll
            for (int i = 0; i < 2; ++i) { ka[i] = kn[i]; va[i] = vn[i]; }
        }
    }
    float* kvp = kvz + (size_t)bh * 4096;
#pragma unroll
    for (int mi = 0; mi < 2; ++mi)
#pragma unroll
        for (int ni = 0; ni < 2; ++ni)
#pragma unroll
            for (int r = 0; r < 4; ++r)
                atomicAdd(kvp + (dh2 * 32 + mi * 16 + quad * 4 + r) * 64
                              + mh2 * 32 + ni * 16 + l15, acc[mi][ni][r]);
    if (mh2 == 0 && l15 == 0) {
#pragma unroll
        for (int mi = 0; mi < 2; ++mi)
#pragma unroll
            for (int r = 0; r < 4; ++r)
                atomicAdd(kvz + KV_ELEMS + bh * 64 + dh2 * 32 + mi * 16 + quad * 4 + r,
                          accz[mi][r]);
    }
}

// ---------------- kv finalize: fp32 kv+z -> bf16 fragment-layout KVf ------------
// KVf[bh] flat order: [ng(5)][kk(2)][quad(4)][l15(16)][j(8)], n=ng*16+l15,
// d=kk*32+quad*8+j; n==64 -> z column, n>64 -> 0 pad.
__global__ void kvf_kernel(const float* __restrict__ kvz, uint16_t* __restrict__ KVf) {
    const int bh = blockIdx.x;
    const int tid = threadIdx.x;
    for (int e = tid; e < 5120; e += 256) {
        const int j = e & 7, c = e >> 3;
        const int l15c = c & 15, quadc = (c >> 4) & 3, kkc = (c >> 6) & 1, ng = c >> 7;
        const int n = ng * 16 + l15c;
        const int d = kkc * 32 + quadc * 8 + j;
        float val = (n < 64) ? kvz[(size_t)bh * 4096 + d * 64 + n]
                  : ((n == 64) ? kvz[KV_ELEMS + bh * 64 + d] : 0.f);
        KVf[(size_t)bh * 5120 + e] = f2bf(val);
    }
}

// ---------------- attention: y = (Q @ kv) / (Q . z + eps), per (b,h) ------------
__global__ __launch_bounds__(256, 4)
void attn_kernel(const uint16_t* __restrict__ Qb, const uint16_t* __restrict__ KVf,
                 uint16_t* __restrict__ Yb)
{
    __shared__ uint4 smem4[1152];             // 10 KB frag + 8 KB epilogue scratch
    uint16_t* sB = (uint16_t*)smem4;          // 5120 entries
    uint16_t* sEp = (uint16_t*)(smem4 + 640);
    const int bh = blockIdx.y;
    const int b = bh >> 3, h = bh & 7;
    const int tid = threadIdx.x;
    const int lane = tid & 63, w = tid >> 6, quad = lane >> 4, l15 = lane & 15;

    const uint16_t* src = KVf + (size_t)bh * 5120;
    gload_lds16(src + (size_t)tid * 8,         sB + (w * 64) * 8);
    gload_lds16(src + (size_t)(256 + tid) * 8, sB + ((256 + w * 64)) * 8);
    if (tid < 128)
        gload_lds16(src + (size_t)(512 + tid) * 8, sB + ((512 + w * 64)) * 8);
    __syncthreads();

    f32x4 acc[2][5];
#pragma unroll
    for (int mi = 0; mi < 2; ++mi)
#pragma unroll
        for (int ni = 0; ni < 5; ++ni) acc[mi][ni] = (f32x4){0.f, 0.f, 0.f, 0.f};
    const int row0 = blockIdx.x * 128 + w * 32;
#pragma unroll
    for (int kk = 0; kk < 2; ++kk) {
        bf16x8 afr[2];
#pragma unroll
        for (int mi = 0; mi < 2; ++mi) {
            const size_t ga = (size_t)(b * S_LEN + row0 + mi * 16 + l15) * DMODEL
                              + h * DHEAD + kk * 32 + quad * 8;
            afr[mi] = *(const bf16x8*)(Qb + ga);
        }
#pragma unroll
        for (int ni = 0; ni < 5; ++ni) {
            bf16x8 bfr = *(const bf16x8*)(sB + ((ni * 2 + kk) * 64 + lane) * 8);
            acc[0][ni] = __builtin_amdgcn_mfma_f32_16x16x32_bf16(afr[0], bfr, acc[0][ni], 0, 0, 0);
            acc[1][ni] = __builtin_amdgcn_mfma_f32_16x16x32_bf16(afr[1], bfr, acc[1][ni], 0, 0, 0);
        }
    }
    uint16_t* t = sEp + w * 1024;
#pragma unroll
    for (int mi = 0; mi < 2; ++mi) {
        float rden[4];
#pragma unroll
        for (int r = 0; r < 4; ++r) {
            const float den = __shfl(acc[mi][4][r], lane & 48, 64);  // col 64 = l15==0
            rden[r] = 1.0f / (den + 1e-6f);
        }
#pragma unroll
        for (int ni = 0; ni < 4; ++ni)
#pragma unroll
            for (int r = 0; r < 4; ++r)
                t[(quad * 4 + r) * 64 + ni * 16 + l15] = f2bf(acc[mi][ni][r] * rden[r]);
#pragma unroll
        for (int c = 0; c < 2; ++c) {
            const int idx = c * 64 + lane;
            const int row = idx >> 3, colc = (idx & 7) * 8;
            uint4 vv = *(const uint4*)(t + row * 64 + colc);
            *(uint4*)(Yb + (size_t)(b * S_LEN + row0 + mi * 16 + row) * 512
                        + h * DHEAD + colc) = vv;
        }
    }
}

extern "C" void kernel_launch(void* const* d_in, const int* in_sizes, int n_in,
                              void* d_out, int out_size, void* d_ws, size_t ws_size,
                              hipStream_t stream)
{
    const float* q  = (const float*)d_in[0];
    const float* k  = (const float*)d_in[1];
    const float* v  = (const float*)d_in[2];
    const float* Wq = (const float*)d_in[3];
    const float* bq = (const float*)d_in[4];
    const float* Wk = (const float*)d_in[5];
    const float* bk = (const float*)d_in[6];
    const float* Wv = (const float*)d_in[7];
    const float* bv = (const float*)d_in[8];
    const float* Wo = (const float*)d_in[9];
    const float* bo = (const float*)d_in[10];

    uint16_t* Qb = (uint16_t*)d_ws;          // bf16 [32768][512]
    uint16_t* KT = Qb + OUT0_ELEMS;          // bf16 [4][512][8192] keys^T
    uint16_t* VT = KT + OUT0_ELEMS;          // bf16 [4][512][8192] values^T
    uint16_t* Wb = VT + OUT0_ELEMS;          // 4 x [512][512] bf16
    uint16_t* KVf = VT;                      // VT dead after kv_kernel -> reuse
    uint16_t* Yb = KT;                       // KT dead after kv_kernel -> reuse

    float* out0 = (float*)d_out;
    float* kvz  = out0 + OUT0_ELEMS;         // kv (131072) then z (2048)

    hipMemsetAsync(kvz, 0, (KV_ELEMS + Z_ELEMS) * sizeof(float), stream);
    wconv_kernel<<<dim3(256, 4), 256, 0, stream>>>(Wq, Wk, Wv, Wo, Wb);
    gemm_kernel<true, true,  false, false><<<dim3(256, 4), 256, 0, stream>>>(q, Wb,              bq, Qb);
    gemm_kernel<true, true,  false, true ><<<dim3(256, 4), 256, 0, stream>>>(k, Wb + 262144,     bk, KT);
    gemm_kernel<true, false, false, true ><<<dim3(256, 4), 256, 0, stream>>>(v, Wb + 2 * 262144, bv, VT);
    kv_kernel<<<dim3(16, 32), 256, 0, stream>>>(KT, VT, kvz);
    kvf_kernel<<<dim3(32), 256, 0, stream>>>(kvz, KVf);
    attn_kernel<<<dim3(64, 32), 256, 0, stream>>>(Qb, KVf, Yb);
    gemm_kernel<false, false, true, false><<<dim3(256, 4), 256, 0, stream>>>(Yb, Wb + 3 * 262144, bo, out0);
}

// Round 5
// 377.748 us; speedup vs baseline: 1.3265x; 1.1398x over previous
//
#include <hip/hip_runtime.h>
#include <hip/hip_bf16.h>
#include <stdint.h>

typedef __bf16 bf16x8 __attribute__((ext_vector_type(8)));
typedef float f32x4 __attribute__((ext_vector_type(4)));

#define S_LEN 8192
#define BATCH 4
#define DMODEL 512
#define NHEAD 8
#define DHEAD 64
#define MROWS (BATCH * S_LEN)              // 32768
#define OUT0_ELEMS (MROWS * DMODEL)        // 16777216
#define KV_ELEMS (BATCH * NHEAD * DHEAD * DHEAD)  // 131072
#define Z_ELEMS (BATCH * NHEAD * DHEAD)    // 2048

// counted waits + raw barrier (T4): loads stay in flight ACROSS barriers.
// "memory" clobbers / empty-asm fences pin compiler ordering (guide rule #18, m201).
#define WAITV6() asm volatile("s_waitcnt vmcnt(6)" ::: "memory")
#define WAITV4() asm volatile("s_waitcnt vmcnt(4)" ::: "memory")
#define WAITV2() asm volatile("s_waitcnt vmcnt(2)" ::: "memory")
#define WAITV0() asm volatile("s_waitcnt vmcnt(0)" ::: "memory")
#define WAITL0() asm volatile("s_waitcnt lgkmcnt(0)" ::: "memory")
#define BARRIER() do { asm volatile("" ::: "memory"); \
                       __builtin_amdgcn_s_barrier(); \
                       asm volatile("" ::: "memory"); } while (0)

__device__ __forceinline__ uint16_t f2bf(float f) {
    uint32_t u = __float_as_uint(f);
    u = (u + 0x7fffu + ((u >> 16) & 1u)) >> 16;   // RNE
    return (uint16_t)u;
}
__device__ __forceinline__ uint32_t pack2(float a, float b) {
    union { __hip_bfloat162 h; uint32_t u; } cv;
    cv.h = __float22bfloat162_rn(make_float2(a, b));
    return cv.u;
}
__device__ __forceinline__ void gload_lds16(const void* g, void* l) {
    __builtin_amdgcn_global_load_lds(
        (const __attribute__((address_space(1))) void*)g,
        (__attribute__((address_space(3))) void*)l, 16, 0, 0);
}

// ---------------- weights fp32 -> bf16 (all four at once) ----------------
__global__ void wconv_kernel(const float* __restrict__ w0, const float* __restrict__ w1,
                             const float* __restrict__ w2, const float* __restrict__ w3,
                             uint16_t* __restrict__ dst) {
    const float* src = (blockIdx.y == 0) ? w0 : (blockIdx.y == 1) ? w1
                       : (blockIdx.y == 2) ? w2 : w3;
    uint16_t* d = dst + (size_t)blockIdx.y * (DMODEL * DMODEL);
    int i = (blockIdx.x * 256 + threadIdx.x) * 4;
    float4 v = *(const float4*)(src + i);
    uint2 o;
    o.x = pack2(v.x, v.y);
    o.y = pack2(v.z, v.w);
    *(uint2*)(d + i) = o;
}

// ---------------- merged q/k/v GEMM: C = act(A @ W^T + b) ----------------------
// 128x128 tile, BK=32, 4 waves each 64x64. Double-buffered 8KB A/B tiles (32 KB).
// K-step t: {stageB(t+1); loadA_reg(t+2); packA(t+1); vmcnt(6); lgkmcnt(0);
//            s_barrier; compute(t); s_barrier} — counted vmcnt leaves next-tile
// loads IN FLIGHT across both barriers (no vmcnt(0) drain; __syncthreads would
// drain). Correctness: vmcnt in-order completion => waiting for loadA(t+1)
// (pack operand, issued AFTER stageB(t)) implies stageB(t) landed; lgkmcnt(0)
// makes my ds_writes visible before the barrier; post-compute barrier (no waits)
// fences buffer reuse.
// Grid (m=256, y=12): y>>2 = {q,k,v}, y&3 = n-block. id%8 = x%8 -> all 12
// y-blocks of an m-tile land on the same XCD (L2 reuse of A rows).
__global__ __launch_bounds__(256, 3)
void gemm_qkv_kernel(const float* __restrict__ qp, const float* __restrict__ kp,
                     const float* __restrict__ vp, const uint16_t* __restrict__ Wb,
                     const float* __restrict__ bq, const float* __restrict__ bk,
                     const float* __restrict__ bv,
                     uint16_t* __restrict__ Qb, uint16_t* __restrict__ KT,
                     uint16_t* __restrict__ VT)
{
    __shared__ uint4 smem4[2048];            // 32 KB: 2x(sA 8K + sB 8K); epilogue scratch
    uint16_t* sAb[2] = {(uint16_t*)smem4, (uint16_t*)smem4 + 8192};
    uint16_t* sBb[2] = {(uint16_t*)smem4 + 4096, (uint16_t*)smem4 + 12288};
    const int tid = threadIdx.x;
    const int lane = tid & 63, w = tid >> 6;
    const int quad = lane >> 4, l15 = lane & 15;
    const int which = blockIdx.y >> 2;
    const int m_blk = blockIdx.x * 128, n_blk = (blockIdx.y & 3) * 128;
    const int g0 = w * 2;                    // this wave's two staging groups

    const float* Af = (which == 0) ? qp : (which == 1) ? kp : vp;
    const float* bias = (which == 0) ? bq : (which == 1) ? bk : bv;
    const uint16_t* Wm = Wb + (size_t)which * 262144;

    f32x4 acc[4][4];
#pragma unroll
    for (int mi = 0; mi < 4; ++mi)
#pragma unroll
        for (int ni = 0; ni < 4; ++ni) acc[mi][ni] = (f32x4){0.f, 0.f, 0.f, 0.f};

    const int ar = tid >> 1;                 // A staging: row 0..127
    const int ah = tid & 1;                  // k-half (16 cols)
    const float* arow_base = Af + (size_t)(m_blk + ar) * 512 + ah * 16;

    auto loadA = [&](int t, float4* r) {
        const float* p = arow_base + t * 32;
        r[0] = *(const float4*)(p);
        r[1] = *(const float4*)(p + 4);
        r[2] = *(const float4*)(p + 8);
        r[3] = *(const float4*)(p + 12);
    };
    auto packA = [&](uint16_t* sA, const float4* r) {
        uint16_t* base = sA + (((ar >> 4) * 4 + ah * 2) * 16 + (ar & 15)) * 8;
        *(uint4*)base = make_uint4(pack2(r[0].x, r[0].y), pack2(r[0].z, r[0].w),
                                   pack2(r[1].x, r[1].y), pack2(r[1].z, r[1].w));
        *(uint4*)(base + 128) = make_uint4(pack2(r[2].x, r[2].y), pack2(r[2].z, r[2].w),
                                           pack2(r[3].x, r[3].y), pack2(r[3].z, r[3].w));
    };
    auto stageB = [&](uint16_t* sB, int t) {
        const int k0 = t * 32;
        gload_lds16(Wm + (size_t)(n_blk + g0 * 16 + l15) * 512 + k0 + quad * 8,
                    sB + g0 * 512);
        gload_lds16(Wm + (size_t)(n_blk + (g0 + 1) * 16 + l15) * 512 + k0 + quad * 8,
                    sB + (g0 + 1) * 512);
    };
    auto compute = [&](const uint16_t* sA, const uint16_t* sB) {
        bf16x8 afr[4], bfr[4];
#pragma unroll
        for (int mi = 0; mi < 4; ++mi)
            afr[mi] = *(const bf16x8*)(sA + (((w & 1) * 4 + mi) * 64 + lane) * 8);
#pragma unroll
        for (int ni = 0; ni < 4; ++ni)
            bfr[ni] = *(const bf16x8*)(sB + (((w >> 1) * 4 + ni) * 64 + lane) * 8);
#pragma unroll
        for (int mi = 0; mi < 4; ++mi)
#pragma unroll
            for (int ni = 0; ni < 4; ++ni)
                acc[mi][ni] = __builtin_amdgcn_mfma_f32_16x16x32_bf16(
                    afr[mi], bfr[ni], acc[mi][ni], 0, 0, 0);
    };

    // Prologue: stageB(0) FIRST, then loadA(0) — pack's operand wait then implies
    // stageB(0) completion (in-order vmcnt). rA[(t+1)&1] holds A(t+1) at step t.
    float4 rA[2][4];
    stageB(sBb[0], 0);
    loadA(0, rA[0]);
    packA(sAb[0], rA[0]);        // compiler waits for loadA(0) => stageB(0) landed
    loadA(1, rA[1]);

#pragma unroll
    for (int t = 0; t < 16; ++t) {
        const int cur = t & 1, nxt = cur ^ 1;
        if (t < 15) stageB(sBb[nxt], t + 1);     // 2 gload (issued before loadA!)
        if (t < 14) loadA(t + 2, rA[cur]);       // 4 gload -> regs
        if (t < 15) packA(sAb[nxt], rA[nxt]);    // waits loadA(t+1) => stageB(t) done
        if (t < 14)      { WAITV6(); }           // leave next-tile 6 in flight
        else if (t == 14){ WAITV2(); }
        else             { WAITV0(); }
        WAITL0();                                // my ds_writes visible
        BARRIER();                               // tile t fully in LDS (all waves)
        compute(sAb[cur], sBb[cur]);
        BARRIER();                               // all reads of tile t done
    }
    __syncthreads();             // defensive; k-loop LDS dead -> epilogue scratch

    const int mw = (w & 1) * 64, nw = (w >> 1) * 64;
    const bool elu = (which != 2);
    float bias4[4];
#pragma unroll
    for (int ni = 0; ni < 4; ++ni) bias4[ni] = bias[n_blk + nw + ni * 16 + l15];

    if (which == 0) {
        // plain bf16 [m][n] out to Qb
        uint16_t* t = (uint16_t*)smem4 + w * 2048;
        uint16_t* C = Qb;
#pragma unroll
        for (int mi = 0; mi < 4; ++mi) {
#pragma unroll
            for (int ni = 0; ni < 4; ++ni)
#pragma unroll
                for (int r = 0; r < 4; ++r) {
                    float val = acc[mi][ni][r] + bias4[ni];
                    val = (val > 0.f) ? (val + 1.f) : __expf(val);
                    t[(quad * 4 + r) * 64 + ni * 16 + l15] = f2bf(val);
                }
#pragma unroll
            for (int c = 0; c < 2; ++c) {
                const int idx = c * 64 + lane;
                const int row = idx >> 3, colc = (idx & 7) * 8;
                uint4 vv = *(const uint4*)(t + row * 64 + colc);
                *(uint4*)(C + (size_t)(m_blk + mw + mi * 16 + row) * 512
                            + n_blk + nw + colc) = vv;
            }
        }
    } else {
        // transposed bf16 [b][n][s] out to KT/VT
        uint16_t* t = (uint16_t*)smem4 + w * 2560;
        uint16_t* C = (which == 1) ? KT : VT;
        const int bb = m_blk >> 13;
        const int s_base = (m_blk & 8191) + mw;
#pragma unroll
        for (int p = 0; p < 2; ++p) {
#pragma unroll
            for (int mi2 = 0; mi2 < 2; ++mi2) {
                const int mi = p * 2 + mi2;
#pragma unroll
                for (int ni = 0; ni < 4; ++ni)
#pragma unroll
                    for (int r = 0; r < 4; ++r) {
                        float val = acc[mi][ni][r] + bias4[ni];
                        if (elu) val = (val > 0.f) ? (val + 1.f) : __expf(val);
                        t[(ni * 16 + l15) * 40 + mi2 * 16 + quad * 4 + r] = f2bf(val);
                    }
            }
#pragma unroll
            for (int it = 0; it < 4; ++it) {
                const int idx = it * 64 + lane;
                const int col = idx >> 2, sg = idx & 3;
                uint4 vv = *(const uint4*)(t + col * 40 + sg * 8);
                *(uint4*)(C + ((size_t)(bb * 512) + n_blk + nw + col) * 8192
                            + s_base + p * 32 + sg * 8) = vv;
            }
        }
    }
}

// ---------------- output GEMM: out0 = Yb @ Wo^T + bo (A bf16, C fp32) -----------
// Same counted-vmcnt schedule; staging is pure gload_lds (4/step): vmcnt(4).
__global__ __launch_bounds__(256, 3)
void gemm_out_kernel(const uint16_t* __restrict__ Ab, const uint16_t* __restrict__ Wm,
                     const float* __restrict__ bias, float* __restrict__ C)
{
    __shared__ uint4 smem4[2048];
    uint16_t* sAb[2] = {(uint16_t*)smem4, (uint16_t*)smem4 + 8192};
    uint16_t* sBb[2] = {(uint16_t*)smem4 + 4096, (uint16_t*)smem4 + 12288};
    const int tid = threadIdx.x;
    const int lane = tid & 63, w = tid >> 6;
    const int quad = lane >> 4, l15 = lane & 15;
    const int m_blk = blockIdx.x * 128, n_blk = blockIdx.y * 128;
    const int g0 = w * 2;

    f32x4 acc[4][4];
#pragma unroll
    for (int mi = 0; mi < 4; ++mi)
#pragma unroll
        for (int ni = 0; ni < 4; ++ni) acc[mi][ni] = (f32x4){0.f, 0.f, 0.f, 0.f};

    auto stageA = [&](uint16_t* sA, int t) {
        const int k0 = t * 32;
        gload_lds16(Ab + (size_t)(m_blk + g0 * 16 + l15) * 512 + k0 + quad * 8,
                    sA + g0 * 512);
        gload_lds16(Ab + (size_t)(m_blk + (g0 + 1) * 16 + l15) * 512 + k0 + quad * 8,
                    sA + (g0 + 1) * 512);
    };
    auto stageB = [&](uint16_t* sB, int t) {
        const int k0 = t * 32;
        gload_lds16(Wm + (size_t)(n_blk + g0 * 16 + l15) * 512 + k0 + quad * 8,
                    sB + g0 * 512);
        gload_lds16(Wm + (size_t)(n_blk + (g0 + 1) * 16 + l15) * 512 + k0 + quad * 8,
                    sB + (g0 + 1) * 512);
    };
    auto compute = [&](const uint16_t* sA, const uint16_t* sB) {
        bf16x8 afr[4], bfr[4];
#pragma unroll
        for (int mi = 0; mi < 4; ++mi)
            afr[mi] = *(const bf16x8*)(sA + (((w & 1) * 4 + mi) * 64 + lane) * 8);
#pragma unroll
        for (int ni = 0; ni < 4; ++ni)
            bfr[ni] = *(const bf16x8*)(sB + (((w >> 1) * 4 + ni) * 64 + lane) * 8);
#pragma unroll
        for (int mi = 0; mi < 4; ++mi)
#pragma unroll
            for (int ni = 0; ni < 4; ++ni)
                acc[mi][ni] = __builtin_amdgcn_mfma_f32_16x16x32_bf16(
                    afr[mi], bfr[ni], acc[mi][ni], 0, 0, 0);
    };

    stageA(sAb[0], 0);
    stageB(sBb[0], 0);
#pragma unroll
    for (int t = 0; t < 16; ++t) {
        const int cur = t & 1, nxt = cur ^ 1;
        if (t < 15) { stageA(sAb[nxt], t + 1); stageB(sBb[nxt], t + 1); }
        if (t < 15) { WAITV4(); } else { WAITV0(); }
        BARRIER();
        compute(sAb[cur], sBb[cur]);
        BARRIER();
    }
    __syncthreads();

    const int mw = (w & 1) * 64, nw = (w >> 1) * 64;
    float bias4[4];
#pragma unroll
    for (int ni = 0; ni < 4; ++ni) bias4[ni] = bias[n_blk + nw + ni * 16 + l15];

    float* t = (float*)(smem4 + w * 256);
#pragma unroll
    for (int mi = 0; mi < 4; ++mi) {
#pragma unroll
        for (int ni = 0; ni < 4; ++ni)
#pragma unroll
            for (int r = 0; r < 4; ++r)
                t[(quad * 4 + r) * 64 + ni * 16 + l15] = acc[mi][ni][r] + bias4[ni];
#pragma unroll
        for (int c = 0; c < 4; ++c) {
            const int idx = c * 64 + lane;
            const int row = idx >> 4, colc = (idx & 15) * 4;
            float4 vv = *(const float4*)(t + row * 64 + colc);
            *(float4*)(C + (size_t)(m_blk + mw + mi * 16 + row) * 512
                         + n_blk + nw + colc) = vv;
        }
    }
}

// ---------------- kv state via MFMA: kv[d][m] = sum_s KT[d][s]*VT[m][s] ---------
// Barrier-free, LDS-free: KT/VT row-major along s (the MFMA k-dim) -> fragments
// are contiguous 16B global loads. z folded in via all-ones B fragment.
__global__ __launch_bounds__(256, 4)
void kv_kernel(const uint16_t* __restrict__ KT, const uint16_t* __restrict__ VT,
               float* __restrict__ kvz)
{
    const int tid = threadIdx.x;
    const int lane = tid & 63, w = tid >> 6;
    const int quad = lane >> 4, l15 = lane & 15;
    const int bh = blockIdx.y, b = bh >> 3, h = bh & 7;
    const int dh2 = w & 1, mh2 = w >> 1;
    const int S0 = blockIdx.x * 512;

    const uint16_t* Ka[2];
    const uint16_t* Va[2];
#pragma unroll
    for (int i = 0; i < 2; ++i) {
        Ka[i] = KT + (size_t)(b * 512 + h * 64 + dh2 * 32 + i * 16 + l15) * 8192 + S0 + quad * 8;
        Va[i] = VT + (size_t)(b * 512 + h * 64 + mh2 * 32 + i * 16 + l15) * 8192 + S0 + quad * 8;
    }

    f32x4 acc[2][2], accz[2];
#pragma unroll
    for (int mi = 0; mi < 2; ++mi) {
        accz[mi] = (f32x4){0.f, 0.f, 0.f, 0.f};
#pragma unroll
        for (int ni = 0; ni < 2; ++ni) acc[mi][ni] = (f32x4){0.f, 0.f, 0.f, 0.f};
    }
    bf16x8 ones;
#pragma unroll
    for (int j = 0; j < 8; ++j) ones[j] = (__bf16)1.0f;

    uint4 ka[2], va[2];
#pragma unroll
    for (int i = 0; i < 2; ++i) {
        ka[i] = *(const uint4*)(Ka[i]);
        va[i] = *(const uint4*)(Va[i]);
    }

#pragma unroll
    for (int it = 0; it < 16; ++it) {
        uint4 kn[2], vn[2];
        if (it < 15) {
#pragma unroll
            for (int i = 0; i < 2; ++i) {
                kn[i] = *(const uint4*)(Ka[i] + (it + 1) * 32);
                vn[i] = *(const uint4*)(Va[i] + (it + 1) * 32);
            }
        }
        bf16x8 afr[2], bfr[2];
#pragma unroll
        for (int i = 0; i < 2; ++i) {
            union { uint4 u; bf16x8 v; } ca, cb;
            ca.u = ka[i]; afr[i] = ca.v;
            cb.u = va[i]; bfr[i] = cb.v;
        }
#pragma unroll
        for (int mi = 0; mi < 2; ++mi)
#pragma unroll
            for (int ni = 0; ni < 2; ++ni)
                acc[mi][ni] = __builtin_amdgcn_mfma_f32_16x16x32_bf16(
                    afr[mi], bfr[ni], acc[mi][ni], 0, 0, 0);
        if (mh2 == 0) {
#pragma unroll
            for (int mi = 0; mi < 2; ++mi)
                accz[mi] = __builtin_amdgcn_mfma_f32_16x16x32_bf16(
                    afr[mi], ones, accz[mi], 0, 0, 0);
        }
        if (it < 15) {
#pragma unroll
            for (int i = 0; i < 2; ++i) { ka[i] = kn[i]; va[i] = vn[i]; }
        }
    }
    float* kvp = kvz + (size_t)bh * 4096;
#pragma unroll
    for (int mi = 0; mi < 2; ++mi)
#pragma unroll
        for (int ni = 0; ni < 2; ++ni)
#pragma unroll
            for (int r = 0; r < 4; ++r)
                atomicAdd(kvp + (dh2 * 32 + mi * 16 + quad * 4 + r) * 64
                              + mh2 * 32 + ni * 16 + l15, acc[mi][ni][r]);
    if (mh2 == 0 && l15 == 0) {
#pragma unroll
        for (int mi = 0; mi < 2; ++mi)
#pragma unroll
            for (int r = 0; r < 4; ++r)
                atomicAdd(kvz + KV_ELEMS + bh * 64 + dh2 * 32 + mi * 16 + quad * 4 + r,
                          accz[mi][r]);
    }
}

// ---------------- kv finalize: fp32 kv+z -> bf16 fragment-layout KVf ------------
__global__ void kvf_kernel(const float* __restrict__ kvz, uint16_t* __restrict__ KVf) {
    const int bh = blockIdx.x;
    const int tid = threadIdx.x;
    for (int e = tid; e < 5120; e += 256) {
        const int j = e & 7, c = e >> 3;
        const int l15c = c & 15, quadc = (c >> 4) & 3, kkc = (c >> 6) & 1, ng = c >> 7;
        const int n = ng * 16 + l15c;
        const int d = kkc * 32 + quadc * 8 + j;
        float val = (n < 64) ? kvz[(size_t)bh * 4096 + d * 64 + n]
                  : ((n == 64) ? kvz[KV_ELEMS + bh * 64 + d] : 0.f);
        KVf[(size_t)bh * 5120 + e] = f2bf(val);
    }
}

// ---------------- attention: y = (Q @ kv) / (Q . z + eps), per (b,h) ------------
__global__ __launch_bounds__(256, 4)
void attn_kernel(const uint16_t* __restrict__ Qb, const uint16_t* __restrict__ KVf,
                 uint16_t* __restrict__ Yb)
{
    __shared__ uint4 smem4[1152];             // 10 KB frag + 8 KB epilogue scratch
    uint16_t* sB = (uint16_t*)smem4;          // 5120 entries
    uint16_t* sEp = (uint16_t*)(smem4 + 640);
    const int bh = blockIdx.y;
    const int b = bh >> 3, h = bh & 7;
    const int tid = threadIdx.x;
    const int lane = tid & 63, w = tid >> 6, quad = lane >> 4, l15 = lane & 15;

    const uint16_t* src = KVf + (size_t)bh * 5120;
    gload_lds16(src + (size_t)tid * 8,         sB + (w * 64) * 8);
    gload_lds16(src + (size_t)(256 + tid) * 8, sB + ((256 + w * 64)) * 8);
    if (tid < 128)
        gload_lds16(src + (size_t)(512 + tid) * 8, sB + ((512 + w * 64)) * 8);
    __syncthreads();

    f32x4 acc[2][5];
#pragma unroll
    for (int mi = 0; mi < 2; ++mi)
#pragma unroll
        for (int ni = 0; ni < 5; ++ni) acc[mi][ni] = (f32x4){0.f, 0.f, 0.f, 0.f};
    const int row0 = blockIdx.x * 128 + w * 32;
#pragma unroll
    for (int kk = 0; kk < 2; ++kk) {
        bf16x8 afr[2];
#pragma unroll
        for (int mi = 0; mi < 2; ++mi) {
            const size_t ga = (size_t)(b * S_LEN + row0 + mi * 16 + l15) * DMODEL
                              + h * DHEAD + kk * 32 + quad * 8;
            afr[mi] = *(const bf16x8*)(Qb + ga);
        }
#pragma unroll
        for (int ni = 0; ni < 5; ++ni) {
            bf16x8 bfr = *(const bf16x8*)(sB + ((ni * 2 + kk) * 64 + lane) * 8);
            acc[0][ni] = __builtin_amdgcn_mfma_f32_16x16x32_bf16(afr[0], bfr, acc[0][ni], 0, 0, 0);
            acc[1][ni] = __builtin_amdgcn_mfma_f32_16x16x32_bf16(afr[1], bfr, acc[1][ni], 0, 0, 0);
        }
    }
    uint16_t* t = sEp + w * 1024;
#pragma unroll
    for (int mi = 0; mi < 2; ++mi) {
        float rden[4];
#pragma unroll
        for (int r = 0; r < 4; ++r) {
            const float den = __shfl(acc[mi][4][r], lane & 48, 64);  // col 64 = l15==0
            rden[r] = 1.0f / (den + 1e-6f);
        }
#pragma unroll
        for (int ni = 0; ni < 4; ++ni)
#pragma unroll
            for (int r = 0; r < 4; ++r)
                t[(quad * 4 + r) * 64 + ni * 16 + l15] = f2bf(acc[mi][ni][r] * rden[r]);
#pragma unroll
        for (int c = 0; c < 2; ++c) {
            const int idx = c * 64 + lane;
            const int row = idx >> 3, colc = (idx & 7) * 8;
            uint4 vv = *(const uint4*)(t + row * 64 + colc);
            *(uint4*)(Yb + (size_t)(b * S_LEN + row0 + mi * 16 + row) * 512
                        + h * DHEAD + colc) = vv;
        }
    }
}

extern "C" void kernel_launch(void* const* d_in, const int* in_sizes, int n_in,
                              void* d_out, int out_size, void* d_ws, size_t ws_size,
                              hipStream_t stream)
{
    const float* q  = (const float*)d_in[0];
    const float* k  = (const float*)d_in[1];
    const float* v  = (const float*)d_in[2];
    const float* Wq = (const float*)d_in[3];
    const float* bq = (const float*)d_in[4];
    const float* Wk = (const float*)d_in[5];
    const float* bk = (const float*)d_in[6];
    const float* Wv = (const float*)d_in[7];
    const float* bv = (const float*)d_in[8];
    const float* Wo = (const float*)d_in[9];
    const float* bo = (const float*)d_in[10];

    uint16_t* Qb = (uint16_t*)d_ws;          // bf16 [32768][512]
    uint16_t* KT = Qb + OUT0_ELEMS;          // bf16 [4][512][8192] keys^T
    uint16_t* VT = KT + OUT0_ELEMS;          // bf16 [4][512][8192] values^T
    uint16_t* Wb = VT + OUT0_ELEMS;          // 4 x [512][512] bf16
    uint16_t* KVf = VT;                      // VT dead after kv_kernel -> reuse
    uint16_t* Yb = KT;                       // KT dead after kv_kernel -> reuse

    float* out0 = (float*)d_out;
    float* kvz  = out0 + OUT0_ELEMS;         // kv (131072) then z (2048)

    hipMemsetAsync(kvz, 0, (KV_ELEMS + Z_ELEMS) * sizeof(float), stream);
    wconv_kernel<<<dim3(256, 4), 256, 0, stream>>>(Wq, Wk, Wv, Wo, Wb);
    gemm_qkv_kernel<<<dim3(256, 12), 256, 0, stream>>>(q, k, v, Wb, bq, bk, bv,
                                                       Qb, KT, VT);
    kv_kernel<<<dim3(16, 32), 256, 0, stream>>>(KT, VT, kvz);
    kvf_kernel<<<dim3(32), 256, 0, stream>>>(kvz, KVf);
    attn_kernel<<<dim3(64, 32), 256, 0, stream>>>(Qb, KVf, Yb);
    gemm_out_kernel<<<dim3(256, 4), 256, 0, stream>>>(Yb, Wb + 3 * 262144, bo, out0);
}